// Round 6
// baseline (682.106 us; speedup 1.0000x reference)
//
#include <hip/hip_runtime.h>
#include <math.h>

#ifndef __has_builtin
#define __has_builtin(x) 0
#endif
#if __has_builtin(__builtin_amdgcn_exp2f)
#define EXP2F(x) __builtin_amdgcn_exp2f(x)
#else
#define EXP2F(x) exp2f(x)
#endif

#define L2E  1.44269504088896340736f
#define RL2E 0.69314718055994530942f

#define NBATCH 2
#define NC 21
#define NP 4096
#define KR 35
#define NUM_ITER 5

typedef _Float16 half_t;
typedef _Float16 h8 __attribute__((ext_vector_type(8)));
typedef _Float16 h4 __attribute__((ext_vector_type(4)));
typedef float f4 __attribute__((ext_vector_type(4)));
typedef float f2 __attribute__((ext_vector_type(2)));
#define MFMA16(a, b, c) __builtin_amdgcn_mfma_f32_16x16x32_f16((a), (b), (c), 0, 0, 0)

// packed fp32 math via inline asm (builtin lowering NaN'd — R8/R13)
static __device__ __forceinline__ f2 pk_fma(f2 a, f2 b, f2 c) {
    f2 d;
    asm volatile("v_pk_fma_f32 %0, %1, %2, %3" : "=v"(d) : "v"(a), "v"(b), "v"(c));
    return d;
}
static __device__ __forceinline__ f2 pk_add(f2 a, f2 b) {
    f2 d;
    asm volatile("v_pk_add_f32 %0, %1, %2" : "=v"(d) : "v"(a), "v"(b));
    return d;
}

// ---- tiling: R10-proven ----
#define PTILE 128
#define NPT   32
#define SQ    16
#define CHUNK 256
#define STEPS 8
#define NBBIL (NBATCH * NPT * SQ)   // 1024
#define NBCONV (NBATCH * NC)        // 42 (now blocks [0,42))
#define NBTOT  (NBBIL + NBCONV)
#define SEG_HALVES 256

// ---- ws layout (float offsets) ----
#define OFF_QFEAT 0                  // [NB*P][8] fp32 AoS
#define OFF_QSOA  65536              // [6][NB*P] fp32 SoA planes
#define OFF_UT    114688             // [NB*P][24] fp32 log-unary
#define OFF_QSF   311296             // [NB][21][P] fp32 spatial out
#define OFF_G     483328             // [64][64] fp16 band-gaussian
#define OFF_QH16  485376             // [NB][24][P] fp16 planar q
#define OFF_PART  845824             // [SQ][1024 segs][256] fp16 partials
#define OFF_CNT   2942976            // int counters: 5 iters * 160 ints
#define CNT_STRIDE 160               // [0,64) cntp  [64,66) cntc  [96,160) claim

// ---- LDS: bilat 23040 B, conv 27648 B; reduce tail reuses [0,4096) ----
#define LDS_BYTES 27648
#define QLS_STRIDE 264     // halves (256 data + 8 pad) — R6-proven banking

__global__ __launch_bounds__(256) void setup_kernel(
    const float* __restrict__ unary, const float* __restrict__ ref,
    const float* __restrict__ kstd, float* __restrict__ ws,
    float* __restrict__ outq)
{
    int gid = blockIdx.x * 256 + threadIdx.x;
    if (gid < NUM_ITER * CNT_STRIDE) {
        ((int*)(ws + OFF_CNT))[gid] = 0;       // zero counters/claims every replay
    }
    if (gid < 4096) {
        float s = 0.f;
        for (int t = -KR; t <= KR; ++t) s += expf(-(float)(t * t) * (1.0f / 72.0f));
        int y = gid >> 6, yp = gid & 63;
        int d = y - yp;
        float v = (d >= -KR && d <= KR) ? expf(-(float)(d * d) * (1.0f / 72.0f)) / s : 0.f;
        ((half_t*)(ws + OFF_G))[gid] = (half_t)v;
    }
    if (gid >= NBATCH * NP) return;
    int n = gid >> 12, p = gid & (NP - 1);
    int y = p >> 6, x = p & 63;
    float k0 = kstd[0], k1 = kstd[1], k2 = kstd[2], k3 = kstd[3], k4 = kstd[4];
    const float* rp = ref + n * 3 * NP + p;
    float f0 = (float)y / k0;
    float f1 = (float)x / k1;
    float f2_ = rp[0]      / k2;
    float f3 = rp[NP]     / k3;
    float f4_ = rp[2 * NP] / k4;
    float sq = f0*f0 + f1*f1 + f2_*f2_ + f3*f3 + f4_*f4_;
    float h  = -0.5f * L2E * sq;
    float* qf = ws + OFF_QFEAT + gid * 8;
    qf[0]=L2E*f0; qf[1]=L2E*f1; qf[2]=L2E*f2_; qf[3]=L2E*f3; qf[4]=L2E*f4_;
    qf[5]=h; qf[6]=0.f; qf[7]=0.f;
    float* qs = ws + OFF_QSOA;
    qs[0*8192 + gid] = L2E*f0;  qs[1*8192 + gid] = L2E*f1;
    qs[2*8192 + gid] = L2E*f2_; qs[3*8192 + gid] = L2E*f3;
    qs[4*8192 + gid] = L2E*f4_; qs[5*8192 + gid] = h;

    float U[NC], e[NC];
    const float* up = unary + n * NC * NP + p;
    float m = -1e30f;
    for (int c = 0; c < NC; ++c) {
        float u = up[c * NP];
        u = fminf(fmaxf(u, 1e-5f), 1.0f);
        U[c] = logf(u);
        m = fmaxf(m, U[c]);
    }
    float ssum = 0.f;
    for (int c = 0; c < NC; ++c) { e[c] = EXP2F(L2E * (U[c] - m)); ssum += e[c]; }
    float inv = 1.0f / ssum;
    float* ut = ws + OFF_UT + gid * 24;
    half_t* qh = (half_t*)(ws + OFF_QH16);
    for (int c = 0; c < NC; ++c) {
        float qv = e[c] * inv;
        ut[c] = U[c];
        qh[(n * 24 + c) * NP + p] = (half_t)qv;
        outq[(n * NC + c) * NP + p] = qv;
    }
    ut[21] = 0.f; ut[22] = 0.f; ut[23] = 0.f;
    qh[(n * 24 + 21) * NP + p] = (half_t)0.f;
    qh[(n * 24 + 22) * NP + p] = (half_t)0.f;
    qh[(n * 24 + 23) * NP + p] = (half_t)0.f;
}

// R4-proven reduce+softmax for one (n,pt) — bit-identical summation order.
// Must be called BLOCK-UNIFORMLY (contains __syncthreads).
static __device__ void do_reduce_pt(
    const half_t* __restrict__ part, const float* __restrict__ ut_,
    const float* __restrict__ qsf, float* __restrict__ outq,
    half_t* __restrict__ qh16, char* lds, int n, int pt, int last, int tid)
{
    float* red = (float*)lds;                 // [1024] f32, reuses LDS base
    int lseg = tid >> 6, l = tid & 63;
    for (int wq = 0; wq < 4; ++wq) {
        const half_t* pb = part
            + (size_t)(((n * NPT + pt) * 4 + wq) * 4 + lseg) * SEG_HALVES
            + (size_t)l * 4;
        h4 vv[16];
        #pragma unroll
        for (int s = 0; s < SQ; ++s)
            vv[s] = *(const h4*)(pb + (size_t)s * 1024 * SEG_HALVES);
        float a0 = 0.f, a1 = 0.f, a2 = 0.f, a3 = 0.f;
        #pragma unroll
        for (int s = 0; s < SQ; ++s) {        // same s-order as R4
            a0 += (float)vv[s][0]; a1 += (float)vv[s][1];
            a2 += (float)vv[s][2]; a3 += (float)vv[s][3];
        }
        __syncthreads();                      // LDS safe to overwrite
        *(f4*)(red + tid * 4) = (f4){a0, a1, a2, a3};
        __syncthreads();
        if (tid < 32) {
            int pp = tid;
            int p = pt * PTILE + wq * 32 + pp;
            int gid = n * NP + p;
            int mtl = pp >> 4, mrow = pp & 15;
            int lg2 = mrow >> 2, reg = mrow & 3;
            const float* ut = ut_ + (size_t)gid * 24;
            const float* qs = qsf + (size_t)n * NC * NP + p;
            float e[NC];
            float m = -1e30f;
            #pragma unroll
            for (int c = 0; c < NC; ++c) {
                int cht = c >> 4, chL = c & 15;
                float qb = red[(mtl * 2 + cht) * 256 + (lg2 * 16 + chL) * 4 + reg];
                float li = ut[c] + 4.0f * qb + 2.0f * qs[c * NP];
                e[c] = li;
                m = fmaxf(m, li);
            }
            float ssum = 0.f;
            #pragma unroll
            for (int c = 0; c < NC; ++c) { float v = EXP2F(L2E * (e[c] - m)); e[c] = v; ssum += v; }
            float inv = 1.0f / ssum;
            if (last) {
                #pragma unroll
                for (int c = 0; c < NC; ++c)
                    outq[(size_t)(n * NC + c) * NP + p] = e[c] * inv;
            } else {
                #pragma unroll
                for (int c = 0; c < NC; ++c)
                    qh16[(size_t)(n * 24 + c) * NP + p] = (half_t)(e[c] * inv);
            }
        }
    }
}

// Fused per-iteration dispatch.
// blocks [0,42): separable conv (launched first -> finishes first).
// blocks [42,1066): bilateral s-blocks (verbatim proven inner loop).
// Tail: last-block-out atomic claim -> reduce+softmax (no extra dispatch).
__global__ __launch_bounds__(256) void bilat_conv_kernel(
    const float* __restrict__ qfeatA,
    const float* __restrict__ qsoa,
    half_t* __restrict__ qh16,
    const half_t* __restrict__ gmat,
    half_t* __restrict__ part,
    float* __restrict__ qsf,
    const float* __restrict__ ut_,
    float* __restrict__ outq,
    int* __restrict__ cntbase,
    int it, int last)
{
    __shared__ __align__(16) char lds[LDS_BYTES];
    __shared__ int sflag[2];
    int b = blockIdx.x;
    int tid = threadIdx.x;
    int l = tid & 63, w = tid >> 6;
    int* cnt  = cntbase + it * CNT_STRIDE;     // [0,64) cntp  [64,66) cntc  [96,160) claim

    if (b >= NBCONV) {
        int bb = b - NBCONV;
        int n  = bb & 1;
        int pt = (bb >> 1) & (NPT - 1);
        int s  = bb >> 6;                          // 0..15
        float*  qsoaS = (float*)lds;               // [6][256]  6 KB
        half_t* qls   = (half_t*)(lds + 6144);     // [32][264] 16896 B

        for (int i = tid; i < 6 * (CHUNK / 4); i += 256) {
            int d = i >> 6, g = i & 63;
            *(f4*)(qsoaS + d * CHUNK + g * 4) =
                *(const f4*)(qsoa + (size_t)d * 8192 + n * NP + s * CHUNK + g * 4);
        }
        for (int i = tid; i < 21 * (CHUNK / 8); i += 256) {
            int c = i >> 5, g = i & 31;
            *(h8*)(qls + c * QLS_STRIDE + g * 8) =
                *(const h8*)(qh16 + (size_t)(n * 24 + c) * NP + s * CHUNK + g * 8);
        }
        for (int i = tid; i < 11 * 33; i += 256) {
            int c = 21 + i / 33, g = i % 33;
            *(h8*)(qls + c * QLS_STRIDE + g * 8) = (h8)(half_t)0.f;
        }
        f2 pf2[2][5], ph2[2];
        #pragma unroll
        for (int mt = 0; mt < 2; ++mt) {
            const float* fp = qfeatA + (size_t)(n * NP + pt * PTILE + (w * 2 + mt) * 16 + (l & 15)) * 8;
            #pragma unroll
            for (int i = 0; i < 5; ++i) {
                float v = fp[i] * RL2E;
                pf2[mt][i] = (f2){v, v};
            }
            ph2[mt] = (f2){fp[5], fp[5]};
        }
        f4 acc[2][2];
        #pragma unroll
        for (int mt = 0; mt < 2; ++mt) { acc[mt][0] = (f4)0.f; acc[mt][1] = (f4)0.f; }
        int kq = (l >> 4) * 8;
        __syncthreads();

        for (int step = 0; step < STEPS; ++step) {
            int qbase = step * 32 + kq;
            h8 kv[2];
            #pragma unroll
            for (int hf = 0; hf < 2; ++hf) {
                f4 qf0 = *(const f4*)(qsoaS + 0 * CHUNK + qbase + hf * 4);
                f4 qf1 = *(const f4*)(qsoaS + 1 * CHUNK + qbase + hf * 4);
                f4 qf2 = *(const f4*)(qsoaS + 2 * CHUNK + qbase + hf * 4);
                f4 qf3 = *(const f4*)(qsoaS + 3 * CHUNK + qbase + hf * 4);
                f4 qf4 = *(const f4*)(qsoaS + 4 * CHUNK + qbase + hf * 4);
                f4 qf5 = *(const f4*)(qsoaS + 5 * CHUNK + qbase + hf * 4);
                #pragma unroll
                for (int pr = 0; pr < 2; ++pr) {
                    f2 q0 = {qf0[2*pr], qf0[2*pr+1]};
                    f2 q1 = {qf1[2*pr], qf1[2*pr+1]};
                    f2 q2 = {qf2[2*pr], qf2[2*pr+1]};
                    f2 q3 = {qf3[2*pr], qf3[2*pr+1]};
                    f2 q4 = {qf4[2*pr], qf4[2*pr+1]};
                    f2 qh2 = {qf5[2*pr], qf5[2*pr+1]};
                    #pragma unroll
                    for (int mt = 0; mt < 2; ++mt) {
                        f2 e = pk_add(qh2, ph2[mt]);
                        e = pk_fma(pf2[mt][0], q0, e);
                        e = pk_fma(pf2[mt][1], q1, e);
                        e = pk_fma(pf2[mt][2], q2, e);
                        e = pk_fma(pf2[mt][3], q3, e);
                        e = pk_fma(pf2[mt][4], q4, e);
                        kv[mt][hf * 4 + pr * 2]     = (half_t)EXP2F(e[0]);
                        kv[mt][hf * 4 + pr * 2 + 1] = (half_t)EXP2F(e[1]);
                    }
                }
            }
            h8 bf0 = *(const h8*)(qls + (size_t)(l & 15) * QLS_STRIDE + qbase);
            h8 bf1 = *(const h8*)(qls + (size_t)(16 + (l & 15)) * QLS_STRIDE + qbase);
            #pragma unroll
            for (int mt = 0; mt < 2; ++mt) {
                acc[mt][0] = MFMA16(kv[mt], bf0, acc[mt][0]);
                acc[mt][1] = MFMA16(kv[mt], bf1, acc[mt][1]);
            }
        }
        #pragma unroll
        for (int mt = 0; mt < 2; ++mt) {
            #pragma unroll
            for (int cht = 0; cht < 2; ++cht) {
                int segFlat = ((((s * 2 + n) * NPT + pt) * 4 + w) * 2 + mt) * 2 + cht;
                h4 hv;
                hv[0] = (half_t)acc[mt][cht][0];
                hv[1] = (half_t)acc[mt][cht][1];
                hv[2] = (half_t)acc[mt][cht][2];
                hv[3] = (half_t)acc[mt][cht][3];
                *(h4*)(part + (size_t)segFlat * SEG_HALVES + l * 4) = hv;
            }
        }

        // ---- last-block-out claim: 16th s-block of (n,pt) reduces it ----
        __threadfence();
        if (tid == 0) {
            int flag = 0;
            if (atomicAdd(&cnt[n * NPT + pt], 1) == SQ - 1) {
                if (atomicAdd(&cnt[64 + n], 0) == NC) {          // conv done?
                    if (atomicExch(&cnt[96 + n * NPT + pt], 1) == 0) flag = 1;
                }
            }
            sflag[0] = flag;
        }
        __syncthreads();
        if (sflag[0]) {
            __threadfence();
            do_reduce_pt(part, ut_, qsf, outq, qh16, lds, n, pt, last, tid);
        }
    } else {
        // ---- conv block: one (n,c); qsf = G * Q * G ----
        int n = b / NC, c = b % NC;
        half_t* qt = (half_t*)lds;
        half_t* gl = (half_t*)(lds + 9216);
        half_t* dl = (half_t*)(lds + 18432);

        for (int i = tid; i < 512; i += 256) {
            int row = i >> 3, g = i & 7;
            *(h8*)(gl + row * 72 + g * 8) = *(const h8*)(gmat + row * 64 + g * 8);
        }
        const half_t* qsrc = qh16 + (size_t)(n * 24 + c) * NP;
        for (int i = tid; i < 512; i += 256) {
            int row = i >> 3, g = i & 7;
            h8 v = *(const h8*)(qsrc + row * 64 + g * 8);
            #pragma unroll
            for (int k = 0; k < 8; ++k) qt[(g * 8 + k) * 72 + row] = v[k];
        }
        __syncthreads();

        int m0 = w * 16;
        f4 acc1[4];
        #pragma unroll
        for (int nt = 0; nt < 4; ++nt) acc1[nt] = (f4)0.f;
        #pragma unroll
        for (int ks = 0; ks < 2; ++ks) {
            h8 af = *(const h8*)(gl + (size_t)(m0 + (l & 15)) * 72 + ks * 32 + (l >> 4) * 8);
            #pragma unroll
            for (int nt = 0; nt < 4; ++nt) {
                h8 bf = *(const h8*)(qt + (size_t)(nt * 16 + (l & 15)) * 72 + ks * 32 + (l >> 4) * 8);
                acc1[nt] = MFMA16(af, bf, acc1[nt]);
            }
        }
        #pragma unroll
        for (int nt = 0; nt < 4; ++nt)
            #pragma unroll
            for (int r = 0; r < 4; ++r)
                dl[(size_t)(m0 + (l >> 4) * 4 + r) * 72 + nt * 16 + (l & 15)] = (half_t)acc1[nt][r];
        __syncthreads();

        f4 acc2[4];
        #pragma unroll
        for (int nt = 0; nt < 4; ++nt) acc2[nt] = (f4)0.f;
        #pragma unroll
        for (int ks = 0; ks < 2; ++ks) {
            h8 af = *(const h8*)(dl + (size_t)(m0 + (l & 15)) * 72 + ks * 32 + (l >> 4) * 8);
            #pragma unroll
            for (int nt = 0; nt < 4; ++nt) {
                h8 bf = *(const h8*)(gl + (size_t)(nt * 16 + (l & 15)) * 72 + ks * 32 + (l >> 4) * 8);
                acc2[nt] = MFMA16(af, bf, acc2[nt]);
            }
        }
        float* dst = qsf + (size_t)(n * NC + c) * NP;
        #pragma unroll
        for (int nt = 0; nt < 4; ++nt)
            #pragma unroll
            for (int r = 0; r < 4; ++r)
                dst[(size_t)(m0 + (l >> 4) * 4 + r) * 64 + nt * 16 + (l & 15)] = acc2[nt][r];

        // ---- conv completion + backstop sweep (rarely reduces anything) ----
        __threadfence();
        if (tid == 0) sflag[0] = (atomicAdd(&cnt[64 + n], 1) == NC - 1) ? 1 : 0;
        __syncthreads();
        if (sflag[0]) {
            for (int pt2 = 0; pt2 < NPT; ++pt2) {
                if (tid == 0) {
                    int ok = 0;
                    if (atomicAdd(&cnt[n * NPT + pt2], 0) == SQ) {
                        if (atomicExch(&cnt[96 + n * NPT + pt2], 1) == 0) ok = 1;
                    }
                    sflag[1] = ok;
                }
                __syncthreads();
                if (sflag[1]) {
                    __threadfence();
                    do_reduce_pt(part, ut_, qsf, outq, qh16, lds, n, pt2, last, tid);
                }
                __syncthreads();
            }
        }
    }
}

extern "C" void kernel_launch(void* const* d_in, const int* in_sizes, int n_in,
                              void* d_out, int out_size, void* d_ws, size_t ws_size,
                              hipStream_t stream)
{
    const float* unary = (const float*)d_in[0];
    const float* ref   = (const float*)d_in[1];
    const float* kstd  = (const float*)d_in[3];
    float* ws   = (float*)d_ws;
    float* outq = (float*)d_out;

    const float*  qfeatA = ws + OFF_QFEAT;
    const float*  qsoa   = ws + OFF_QSOA;
    float*        ut     = ws + OFF_UT;
    float*        qsf    = ws + OFF_QSF;
    const half_t* gmat   = (const half_t*)(ws + OFF_G);
    half_t*       qh16   = (half_t*)(ws + OFF_QH16);
    half_t*       part   = (half_t*)(ws + OFF_PART);
    int*          cnt    = (int*)(ws + OFF_CNT);

    setup_kernel<<<32, 256, 0, stream>>>(unary, ref, kstd, ws, outq);
    for (int it = 0; it < NUM_ITER; ++it) {
        bilat_conv_kernel<<<NBTOT, 256, 0, stream>>>(
            qfeatA, qsoa, qh16, gmat, part, qsf, ut, outq, cnt,
            it, it == NUM_ITER - 1 ? 1 : 0);
    }
}

// Round 7
// 144.385 us; speedup vs baseline: 4.7242x; 4.7242x over previous
//
#include <hip/hip_runtime.h>
#include <math.h>

#ifndef __has_builtin
#define __has_builtin(x) 0
#endif
#if __has_builtin(__builtin_amdgcn_exp2f)
#define EXP2F(x) __builtin_amdgcn_exp2f(x)
#else
#define EXP2F(x) exp2f(x)
#endif

#define L2E  1.44269504088896340736f
#define RL2E 0.69314718055994530942f

#define NBATCH 2
#define NC 21
#define NP 4096
#define KR 35
#define NUM_ITER 5

typedef _Float16 half_t;
typedef _Float16 h8 __attribute__((ext_vector_type(8)));
typedef _Float16 h4 __attribute__((ext_vector_type(4)));
typedef float f4 __attribute__((ext_vector_type(4)));
typedef float f2 __attribute__((ext_vector_type(2)));
#define MFMA16(a, b, c) __builtin_amdgcn_mfma_f32_16x16x32_f16((a), (b), (c), 0, 0, 0)

// packed fp32 math via inline asm (builtin lowering NaN'd — R8/R13)
static __device__ __forceinline__ f2 pk_fma(f2 a, f2 b, f2 c) {
    f2 d;
    asm volatile("v_pk_fma_f32 %0, %1, %2, %3" : "=v"(d) : "v"(a), "v"(b), "v"(c));
    return d;
}
static __device__ __forceinline__ f2 pk_add(f2 a, f2 b) {
    f2 d;
    asm volatile("v_pk_add_f32 %0, %1, %2" : "=v"(d) : "v"(a), "v"(b));
    return d;
}

// ---- tiling: R6 = R4 structure with PTILE 256 (4 m-tiles per wave) ----
#define PTILE 256          // p per block (4 m-tiles per wave)
#define NPT   16
#define MTW   4            // m-tiles per wave
#define SQ    16           // q-splits -> chunk = 256 q
#define CHUNK 256
#define STEPS 8            // CHUNK/32
#define NBBIL (NBATCH * NPT * SQ)   // 512
#define NBCONV (NBATCH * NC)        // 42
#define NBTOT  (NBBIL + NBCONV)     // 554
#define SEG_HALVES 256

// ---- ws layout (float offsets) ----
#define OFF_QFEAT 0                  // [NB*P][8] fp32 AoS {L*f0..L*f4, h, 0,0}
#define OFF_QSOA  65536              // [6][NB*P] fp32 SoA planes
#define OFF_UT    114688             // [NB*P][24] fp32 log-unary
#define OFF_QSF   311296             // [NB][21][P] fp32 spatial out
#define OFF_G     483328             // [64][64] fp16 band-gaussian
#define OFF_QH16  485376             // [NB][24][P] fp16 planar q
#define OFF_PART  845824             // [SQ][1024 segs][256] fp16 partials

// ---- LDS: bilat 23040 B (SoA 6144 + qls 16896), conv 27648 B ----
#define LDS_BYTES 27648
#define QLS_STRIDE 264     // halves (256 data + 8 pad) — R6-proven banking

__global__ __launch_bounds__(256) void setup_kernel(
    const float* __restrict__ unary, const float* __restrict__ ref,
    const float* __restrict__ kstd, float* __restrict__ ws,
    float* __restrict__ outq)
{
    int gid = blockIdx.x * 256 + threadIdx.x;
    if (gid < 4096) {
        float s = 0.f;
        for (int t = -KR; t <= KR; ++t) s += expf(-(float)(t * t) * (1.0f / 72.0f));
        int y = gid >> 6, yp = gid & 63;
        int d = y - yp;
        float v = (d >= -KR && d <= KR) ? expf(-(float)(d * d) * (1.0f / 72.0f)) / s : 0.f;
        ((half_t*)(ws + OFF_G))[gid] = (half_t)v;
    }
    if (gid >= NBATCH * NP) return;
    int n = gid >> 12, p = gid & (NP - 1);
    int y = p >> 6, x = p & 63;
    float k0 = kstd[0], k1 = kstd[1], k2 = kstd[2], k3 = kstd[3], k4 = kstd[4];
    const float* rp = ref + n * 3 * NP + p;
    float f0 = (float)y / k0;
    float f1 = (float)x / k1;
    float f2_ = rp[0]      / k2;
    float f3 = rp[NP]     / k3;
    float f4_ = rp[2 * NP] / k4;
    float sq = f0*f0 + f1*f1 + f2_*f2_ + f3*f3 + f4_*f4_;
    float h  = -0.5f * L2E * sq;       // exp2 exponent offset
    float* qf = ws + OFF_QFEAT + gid * 8;
    qf[0]=L2E*f0; qf[1]=L2E*f1; qf[2]=L2E*f2_; qf[3]=L2E*f3; qf[4]=L2E*f4_;
    qf[5]=h; qf[6]=0.f; qf[7]=0.f;
    float* qs = ws + OFF_QSOA;
    qs[0*8192 + gid] = L2E*f0;  qs[1*8192 + gid] = L2E*f1;
    qs[2*8192 + gid] = L2E*f2_; qs[3*8192 + gid] = L2E*f3;
    qs[4*8192 + gid] = L2E*f4_; qs[5*8192 + gid] = h;

    float U[NC], e[NC];
    const float* up = unary + n * NC * NP + p;
    float m = -1e30f;
    for (int c = 0; c < NC; ++c) {
        float u = up[c * NP];
        u = fminf(fmaxf(u, 1e-5f), 1.0f);
        U[c] = logf(u);
        m = fmaxf(m, U[c]);
    }
    float ssum = 0.f;
    for (int c = 0; c < NC; ++c) { e[c] = EXP2F(L2E * (U[c] - m)); ssum += e[c]; }
    float inv = 1.0f / ssum;
    float* ut = ws + OFF_UT + gid * 24;
    half_t* qh = (half_t*)(ws + OFF_QH16);
    for (int c = 0; c < NC; ++c) {
        float qv = e[c] * inv;
        ut[c] = U[c];
        qh[(n * 24 + c) * NP + p] = (half_t)qv;
        outq[(n * NC + c) * NP + p] = qv;
    }
    ut[21] = 0.f; ut[22] = 0.f; ut[23] = 0.f;
    qh[(n * 24 + 21) * NP + p] = (half_t)0.f;
    qh[(n * 24 + 22) * NP + p] = (half_t)0.f;
    qh[(n * 24 + 23) * NP + p] = (half_t)0.f;
}

// L1: blocks [0,512): bilateral (PTILE=256). blocks [512,554): separable conv.
__global__ __launch_bounds__(256) void bilat_conv_kernel(
    const float* __restrict__ qfeatA,     // AoS (p side)
    const float* __restrict__ qsoa,       // SoA planes (q side)
    const half_t* __restrict__ qh16,
    const half_t* __restrict__ gmat,
    half_t* __restrict__ part,
    float* __restrict__ qsf)
{
    __shared__ __align__(16) char lds[LDS_BYTES];
    int b = blockIdx.x;
    int tid = threadIdx.x;
    int l = tid & 63, w = tid >> 6;

    if (b < NBBIL) {
        int n  = b & 1;
        int pt = (b >> 1) & (NPT - 1);             // 0..15
        int s  = b >> 5;                           // 0..15
        float*  qsoaS = (float*)lds;               // [6][256]  6 KB
        half_t* qls   = (half_t*)(lds + 6144);     // [32][264] 16896 B

        // stage SoA q-features (coalesced per plane)
        for (int i = tid; i < 6 * (CHUNK / 4); i += 256) {   // 384 float4
            int d = i >> 6, g = i & 63;
            *(f4*)(qsoaS + d * CHUNK + g * 4) =
                *(const f4*)(qsoa + (size_t)d * 8192 + n * NP + s * CHUNK + g * 4);
        }
        // stage q-probs fp16 rows 0..20; zero rows 21..31
        for (int i = tid; i < 21 * (CHUNK / 8); i += 256) {  // 672 h8
            int c = i >> 5, g = i & 31;
            *(h8*)(qls + c * QLS_STRIDE + g * 8) =
                *(const h8*)(qh16 + (size_t)(n * 24 + c) * NP + s * CHUNK + g * 8);
        }
        for (int i = tid; i < 11 * 33; i += 256) {           // 363 h8 zeros
            int c = 21 + i / 33, g = i % 33;
            *(h8*)(qls + c * QLS_STRIDE + g * 8) = (h8)(half_t)0.f;
        }
        // p-side features: wave w owns m-tiles w*4+mt (mt=0..3); lane row = l&15
        f2 pf2[MTW][5], ph2[MTW];
        #pragma unroll
        for (int mt = 0; mt < MTW; ++mt) {
            const float* fp = qfeatA + (size_t)(n * NP + pt * PTILE + (w * MTW + mt) * 16 + (l & 15)) * 8;
            #pragma unroll
            for (int i = 0; i < 5; ++i) {
                float v = fp[i] * RL2E;
                pf2[mt][i] = (f2){v, v};
            }
            ph2[mt] = (f2){fp[5], fp[5]};
        }
        f4 acc[MTW][2];
        #pragma unroll
        for (int mt = 0; mt < MTW; ++mt) { acc[mt][0] = (f4)0.f; acc[mt][1] = (f4)0.f; }
        int kq = (l >> 4) * 8;
        __syncthreads();

        for (int step = 0; step < STEPS; ++step) {
            int qbase = step * 32 + kq;
            h8 kv[MTW];
            #pragma unroll
            for (int hf = 0; hf < 2; ++hf) {
                // conflict-free b128 quad reads: this lane's 4 q's, all 6 features
                f4 qf0 = *(const f4*)(qsoaS + 0 * CHUNK + qbase + hf * 4);
                f4 qf1 = *(const f4*)(qsoaS + 1 * CHUNK + qbase + hf * 4);
                f4 qf2 = *(const f4*)(qsoaS + 2 * CHUNK + qbase + hf * 4);
                f4 qf3 = *(const f4*)(qsoaS + 3 * CHUNK + qbase + hf * 4);
                f4 qf4 = *(const f4*)(qsoaS + 4 * CHUNK + qbase + hf * 4);
                f4 qf5 = *(const f4*)(qsoaS + 5 * CHUNK + qbase + hf * 4);
                // packed fp32 fma via asm: two q's per instruction
                #pragma unroll
                for (int pr = 0; pr < 2; ++pr) {
                    f2 q0 = {qf0[2*pr], qf0[2*pr+1]};
                    f2 q1 = {qf1[2*pr], qf1[2*pr+1]};
                    f2 q2 = {qf2[2*pr], qf2[2*pr+1]};
                    f2 q3 = {qf3[2*pr], qf3[2*pr+1]};
                    f2 q4 = {qf4[2*pr], qf4[2*pr+1]};
                    f2 qh2 = {qf5[2*pr], qf5[2*pr+1]};
                    #pragma unroll
                    for (int mt = 0; mt < MTW; ++mt) {
                        f2 e = pk_add(qh2, ph2[mt]);
                        e = pk_fma(pf2[mt][0], q0, e);
                        e = pk_fma(pf2[mt][1], q1, e);
                        e = pk_fma(pf2[mt][2], q2, e);
                        e = pk_fma(pf2[mt][3], q3, e);
                        e = pk_fma(pf2[mt][4], q4, e);
                        kv[mt][hf * 4 + pr * 2]     = (half_t)EXP2F(e[0]);
                        kv[mt][hf * 4 + pr * 2 + 1] = (half_t)EXP2F(e[1]);
                    }
                }
            }
            h8 bf0 = *(const h8*)(qls + (size_t)(l & 15) * QLS_STRIDE + qbase);
            h8 bf1 = *(const h8*)(qls + (size_t)(16 + (l & 15)) * QLS_STRIDE + qbase);
            #pragma unroll
            for (int mt = 0; mt < MTW; ++mt) {
                acc[mt][0] = MFMA16(kv[mt], bf0, acc[mt][0]);
                acc[mt][1] = MFMA16(kv[mt], bf1, acc[mt][1]);
            }
        }
        // epilogue: raw C-fragment partials, fp16, coalesced b64
        // seg = (s*2+n)*512 + pt*32 + w*8 + mt*2 + cht
        #pragma unroll
        for (int mt = 0; mt < MTW; ++mt) {
            #pragma unroll
            for (int cht = 0; cht < 2; ++cht) {
                int segFlat = ((((s * 2 + n) * NPT + pt) * 4 + w) * MTW + mt) * 2 + cht;
                h4 hv;
                hv[0] = (half_t)acc[mt][cht][0];
                hv[1] = (half_t)acc[mt][cht][1];
                hv[2] = (half_t)acc[mt][cht][2];
                hv[3] = (half_t)acc[mt][cht][3];
                *(h4*)(part + (size_t)segFlat * SEG_HALVES + l * 4) = hv;
            }
        }
    } else {
        // ---- conv block: one (n,c); qsf = G * Q * G ----
        int cb = b - NBBIL;
        int n = cb / NC, c = cb % NC;
        half_t* qt = (half_t*)lds;
        half_t* gl = (half_t*)(lds + 9216);
        half_t* dl = (half_t*)(lds + 18432);

        for (int i = tid; i < 512; i += 256) {
            int row = i >> 3, g = i & 7;
            *(h8*)(gl + row * 72 + g * 8) = *(const h8*)(gmat + row * 64 + g * 8);
        }
        const half_t* qsrc = qh16 + (size_t)(n * 24 + c) * NP;
        for (int i = tid; i < 512; i += 256) {
            int row = i >> 3, g = i & 7;
            h8 v = *(const h8*)(qsrc + row * 64 + g * 8);
            #pragma unroll
            for (int k = 0; k < 8; ++k) qt[(g * 8 + k) * 72 + row] = v[k];
        }
        __syncthreads();

        int m0 = w * 16;
        f4 acc1[4];
        #pragma unroll
        for (int nt = 0; nt < 4; ++nt) acc1[nt] = (f4)0.f;
        #pragma unroll
        for (int ks = 0; ks < 2; ++ks) {
            h8 af = *(const h8*)(gl + (size_t)(m0 + (l & 15)) * 72 + ks * 32 + (l >> 4) * 8);
            #pragma unroll
            for (int nt = 0; nt < 4; ++nt) {
                h8 bf = *(const h8*)(qt + (size_t)(nt * 16 + (l & 15)) * 72 + ks * 32 + (l >> 4) * 8);
                acc1[nt] = MFMA16(af, bf, acc1[nt]);
            }
        }
        #pragma unroll
        for (int nt = 0; nt < 4; ++nt)
            #pragma unroll
            for (int r = 0; r < 4; ++r)
                dl[(size_t)(m0 + (l >> 4) * 4 + r) * 72 + nt * 16 + (l & 15)] = (half_t)acc1[nt][r];
        __syncthreads();

        f4 acc2[4];
        #pragma unroll
        for (int nt = 0; nt < 4; ++nt) acc2[nt] = (f4)0.f;
        #pragma unroll
        for (int ks = 0; ks < 2; ++ks) {
            h8 af = *(const h8*)(dl + (size_t)(m0 + (l & 15)) * 72 + ks * 32 + (l >> 4) * 8);
            #pragma unroll
            for (int nt = 0; nt < 4; ++nt) {
                h8 bf = *(const h8*)(gl + (size_t)(nt * 16 + (l & 15)) * 72 + ks * 32 + (l >> 4) * 8);
                acc2[nt] = MFMA16(af, bf, acc2[nt]);
            }
        }
        float* dst = qsf + (size_t)(n * NC + c) * NP;
        #pragma unroll
        for (int nt = 0; nt < 4; ++nt)
            #pragma unroll
            for (int r = 0; r < 4; ++r)
                dst[(size_t)(m0 + (l >> 4) * 4 + r) * 64 + nt * 16 + (l & 15)] = acc2[nt][r];
    }
}

// L2+L3 merged: reduce fp16 partials over s, then per-pixel softmax update.
// 256 blocks: rb -> (n, pt in [0,16), wq in [0,8)); 32 p's per block.
// 16 s-partials preloaded to regs (independent loads), summed in the
// ORIGINAL s-order -> bit-identical.
__global__ __launch_bounds__(256) void reduce_update_kernel(
    const half_t* __restrict__ part, const float* __restrict__ ut_,
    const float* __restrict__ qsf, float* __restrict__ outq,
    half_t* __restrict__ qh16, int last)
{
    __shared__ float red[1024];    // 4 segs * 256
    int rb = blockIdx.x;           // [0,256)
    int tid = threadIdx.x;
    int n = rb & 1, pt = (rb >> 1) & (NPT - 1), wq = rb >> 5;   // wq 0..7
    int w = wq >> 1, mtbase = (wq & 1) * 2;
    int lseg = tid >> 6, l = tid & 63;   // lseg = mtl*2 + cht

    // seg(s) = (s*2+n)*512 + pt*32 + w*8 + mtbase*2 + lseg
    const half_t* pb = part
        + (size_t)(n * 512 + pt * 32 + w * 8 + mtbase * 2 + lseg) * SEG_HALVES
        + (size_t)l * 4;
    h4 vv[16];
    #pragma unroll
    for (int s = 0; s < SQ; ++s)
        vv[s] = *(const h4*)(pb + (size_t)s * 1024 * SEG_HALVES);

    float a0 = 0.f, a1 = 0.f, a2 = 0.f, a3 = 0.f;
    #pragma unroll
    for (int s = 0; s < SQ; ++s) {            // same s-order as R4
        a0 += (float)vv[s][0]; a1 += (float)vv[s][1];
        a2 += (float)vv[s][2]; a3 += (float)vv[s][3];
    }
    *(f4*)(red + tid * 4) = (f4){a0, a1, a2, a3};
    __syncthreads();

    if (tid < 32) {
        int pp = tid;
        int p = pt * PTILE + wq * 32 + pp;
        int gid = n * NP + p;
        int mtl = pp >> 4, mrow = pp & 15;
        int lg2 = mrow >> 2, reg = mrow & 3;

        const float* ut = ut_ + (size_t)gid * 24;
        const float* qs = qsf + (size_t)n * NC * NP + p;
        float e[NC];
        float m = -1e30f;
        #pragma unroll
        for (int c = 0; c < NC; ++c) {
            int cht = c >> 4, chL = c & 15;
            float qb = red[(mtl * 2 + cht) * 256 + (lg2 * 16 + chL) * 4 + reg];
            float li = ut[c] + 4.0f * qb + 2.0f * qs[c * NP];
            e[c] = li;
            m = fmaxf(m, li);
        }
        float ssum = 0.f;
        #pragma unroll
        for (int c = 0; c < NC; ++c) { float v = EXP2F(L2E * (e[c] - m)); e[c] = v; ssum += v; }
        float inv = 1.0f / ssum;
        if (last) {
            #pragma unroll
            for (int c = 0; c < NC; ++c)
                outq[(size_t)(n * NC + c) * NP + p] = e[c] * inv;
        } else {
            #pragma unroll
            for (int c = 0; c < NC; ++c)
                qh16[(size_t)(n * 24 + c) * NP + p] = (half_t)(e[c] * inv);
        }
    }
}

extern "C" void kernel_launch(void* const* d_in, const int* in_sizes, int n_in,
                              void* d_out, int out_size, void* d_ws, size_t ws_size,
                              hipStream_t stream)
{
    const float* unary = (const float*)d_in[0];
    const float* ref   = (const float*)d_in[1];
    const float* kstd  = (const float*)d_in[3];
    float* ws   = (float*)d_ws;
    float* outq = (float*)d_out;

    const float*  qfeatA = ws + OFF_QFEAT;
    const float*  qsoa   = ws + OFF_QSOA;
    float*        ut     = ws + OFF_UT;
    float*        qsf    = ws + OFF_QSF;
    const half_t* gmat   = (const half_t*)(ws + OFF_G);
    half_t*       qh16   = (half_t*)(ws + OFF_QH16);
    half_t*       part   = (half_t*)(ws + OFF_PART);

    setup_kernel<<<32, 256, 0, stream>>>(unary, ref, kstd, ws, outq);
    for (int it = 0; it < NUM_ITER; ++it) {
        bilat_conv_kernel<<<NBTOT, 256, 0, stream>>>(
            qfeatA, qsoa, qh16, gmat, part, qsf);
        reduce_update_kernel<<<256, 256, 0, stream>>>(
            part, ut, qsf, outq, qh16, it == NUM_ITER - 1 ? 1 : 0);
    }
}